// Round 14
// baseline (1105.565 us; speedup 1.0000x reference)
//
#include <hip/hip_runtime.h>
#include <math.h>

#define NSEQ 320
#define HDIM 512
#define G4   2048
#define EMBD 300
#define ELMOD 1024
#define XPAD 832          // 812 padded to multiple of 32
#define BUFU (160*1024)   // ushorts per rotated h step-buffer (160 rows x 1024)

typedef __attribute__((ext_vector_type(8))) short bf16x8;
typedef __attribute__((ext_vector_type(4))) float f32x4;
typedef __attribute__((ext_vector_type(4))) unsigned int u32x4;
typedef unsigned short ushort_t;

__device__ __forceinline__ float sigmoidf_(float x) { return 1.0f / (1.0f + expf(-x)); }

__device__ __forceinline__ ushort_t f2bf(float f) {
    unsigned u = __float_as_uint(f);
    u = (u + 0x7FFFu + ((u >> 16) & 1u)) >> 16;   // RNE
    return (ushort_t)u;
}
__device__ __forceinline__ unsigned pack2(float a, float b) {
    return (unsigned)f2bf(a) | ((unsigned)f2bf(b) << 16);
}

// ---------------- all weight conversions in ONE flat launch ----------------
struct ConvPack {
    const float* src[9];
    ushort_t* dst[9];
    int srcCols[9], dstStride[9], dstOff[9], fillCols[9];
    long base[10];
};

__global__ __launch_bounds__(256) void conv_all_kernel(ConvPack P)
{
    long gid = (long)blockIdx.x * 256 + threadIdx.x;
    if (gid >= P.base[9]) return;
    int job = 0;
    #pragma unroll
    for (int j = 1; j < 9; ++j) if (gid >= P.base[j]) job = j;
    int e  = (int)(gid - P.base[job]);
    int fc = P.fillCols[job];
    int r  = e / fc;
    int ci = e - r * fc;
    int sc = P.srcCols[job];
    float v = (ci < sc) ? P.src[job][(size_t)r * sc + ci] : 0.0f;
    P.dst[job][(size_t)r * P.dstStride[job] + P.dstOff[job] + ci] = f2bf(v);
}

// ---------------- GloVe gather (ques+hist merged) + tokcat ----------------
__global__ __launch_bounds__(128) void emb_gather_kernel(
    const int* __restrict__ ques, const int* __restrict__ hist,
    const float* __restrict__ w_emb, ushort_t* __restrict__ Xb,
    int* __restrict__ tokcat)
{
    int n = blockIdx.x;
    int tokid = (n < 6400) ? ques[n] : hist[n - 6400];
    int t = threadIdx.x;
    ushort_t* dst = Xb + (size_t)n * XPAD;
    if (t < 75) {
        const float4* src = (const float4*)(w_emb + (size_t)tokid * EMBD);
        float4 v = src[t];
        dst[4*t+0] = f2bf(v.x); dst[4*t+1] = f2bf(v.y);
        dst[4*t+2] = f2bf(v.z); dst[4*t+3] = f2bf(v.w);
    } else if (t >= 108) {  // 20 pad cols
        dst[812 + (t - 108)] = 0;
        if (t == 108) tokcat[n] = tokid;
    }
}

// ---------------- feed-forward GEMM (64x64 tile): elmo projection ----------------
__global__ __launch_bounds__(256) void gemm_ff_kernel(
    const ushort_t* __restrict__ Ab, const float* __restrict__ Af,
    const int* __restrict__ tok, int strideA,
    const ushort_t* __restrict__ W, const float* __restrict__ bias,
    ushort_t* __restrict__ C, int strideC, int K, int remap)
{
    __shared__ ushort_t As[64 * 40];
    __shared__ ushort_t Bs[64 * 40];
    const int m0 = blockIdx.y * 64;
    const int n0 = blockIdx.x * 64;
    const int tid = threadIdx.x;
    const int r  = tid >> 2;
    const int kq = (tid & 3) << 3;

    const ushort_t* arow_b = nullptr;
    const float*    arow_f = nullptr;
    if (Af) arow_f = Af + (size_t)tok[m0 + r] * strideA + kq;
    else    arow_b = Ab + (size_t)(m0 + r) * strideA + kq;
    const ushort_t* brow = W + (size_t)(n0 + r) * K + kq;

    const int lane = tid & 63;
    const int w = tid >> 6;
    const int wm = w & 1, wn = w >> 1;
    const int kc = (lane >> 4) << 3;

    f32x4 acc[2][2];
    #pragma unroll
    for (int f = 0; f < 2; ++f)
        #pragma unroll
        for (int g = 0; g < 2; ++g)
            acc[f][g] = (f32x4){0.f, 0.f, 0.f, 0.f};

    for (int k0 = 0; k0 < K; k0 += 32) {
        if (Af) {
            float4 v0 = ((const float4*)(arow_f + k0))[0];
            float4 v1 = ((const float4*)(arow_f + k0))[1];
            uint4 p; p.x = pack2(v0.x, v0.y); p.y = pack2(v0.z, v0.w);
            p.z = pack2(v1.x, v1.y); p.w = pack2(v1.z, v1.w);
            *(uint4*)&As[r*40 + kq] = p;
        } else {
            *(uint4*)&As[r*40 + kq] = *(const uint4*)(arow_b + k0);
        }
        *(uint4*)&Bs[r*40 + kq] = *(const uint4*)(brow + k0);
        __syncthreads();
        bf16x8 af[2], bfr[2];
        #pragma unroll
        for (int f = 0; f < 2; ++f)
            af[f] = *(const bf16x8*)&As[(wm*32 + f*16 + (lane & 15))*40 + kc];
        #pragma unroll
        for (int g = 0; g < 2; ++g)
            bfr[g] = *(const bf16x8*)&Bs[(wn*32 + g*16 + (lane & 15))*40 + kc];
        #pragma unroll
        for (int f = 0; f < 2; ++f)
            #pragma unroll
            for (int g = 0; g < 2; ++g)
                acc[f][g] = __builtin_amdgcn_mfma_f32_16x16x32_bf16(af[f], bfr[g], acc[f][g], 0, 0, 0);
        __syncthreads();
    }

    #pragma unroll
    for (int f = 0; f < 2; ++f) {
        #pragma unroll
        for (int g = 0; g < 2; ++g) {
            int col = n0 + wn*32 + g*16 + (lane & 15);
            float bv = bias[col];
            int colw = remap ? ((col & 511) * 4 + (col >> 9)) : col;
            #pragma unroll
            for (int i = 0; i < 4; ++i) {
                int row = m0 + wm*32 + f*16 + ((lane >> 4) << 2) + i;
                C[(size_t)row * strideC + colw] = f2bf(acc[f][g][i] + bv);
            }
        }
    }
}

// ---------------- XP0 GEMM: 128x128 tile, global_load_lds staging ----------------
__global__ __launch_bounds__(256) void gemm_xp_kernel(
    const ushort_t* __restrict__ A,       // bf16 [M][XPAD]
    const ushort_t* __restrict__ W,       // bf16 [2048][XPAD]
    const float* __restrict__ bias,       // [2048]
    ushort_t* __restrict__ C)             // [M][2048] gate-interleaved cols
{
    __shared__ ushort_t As[128 * 32];
    __shared__ ushort_t Bs[128 * 32];
    const int m0 = blockIdx.y * 128;
    const int n0 = blockIdx.x * 128;
    const int tid = threadIdx.x;
    const int w = tid >> 6, lane = tid & 63;
    const int wm = w & 1, wn = w >> 1;
    const int cc = lane & 15, kg = lane >> 4;
    const int srow = lane >> 2;
    const int skc  = lane & 3;

    f32x4 acc[4][4];
    #pragma unroll
    for (int f = 0; f < 4; ++f)
        #pragma unroll
        for (int g = 0; g < 4; ++g)
            acc[f][g] = (f32x4){0.f, 0.f, 0.f, 0.f};

    for (int k0 = 0; k0 < XPAD; k0 += 32) {
        __syncthreads();
        #pragma unroll
        for (int i = 0; i < 2; ++i) {
            const int r = w*16 + i*64;
            const ushort_t* ga = A + (size_t)(m0 + r + srow) * XPAD + k0 + skc*8;
            ushort_t* la = &As[r * 32];
            __builtin_amdgcn_global_load_lds(
                (const __attribute__((address_space(1))) unsigned int*)ga,
                (__attribute__((address_space(3))) unsigned int*)la, 16, 0, 0);
            const ushort_t* gb = W + (size_t)(n0 + r + srow) * XPAD + k0 + skc*8;
            ushort_t* lb = &Bs[r * 32];
            __builtin_amdgcn_global_load_lds(
                (const __attribute__((address_space(1))) unsigned int*)gb,
                (__attribute__((address_space(3))) unsigned int*)lb, 16, 0, 0);
        }
        asm volatile("s_waitcnt vmcnt(0)");
        __syncthreads();
        bf16x8 af[4], bfr[4];
        #pragma unroll
        for (int f = 0; f < 4; ++f)
            af[f] = *(const bf16x8*)&As[(wm*64 + f*16 + cc)*32 + kg*8];
        #pragma unroll
        for (int g = 0; g < 4; ++g)
            bfr[g] = *(const bf16x8*)&Bs[(wn*64 + g*16 + cc)*32 + kg*8];
        #pragma unroll
        for (int f = 0; f < 4; ++f)
            #pragma unroll
            for (int g = 0; g < 4; ++g)
                acc[f][g] = __builtin_amdgcn_mfma_f32_16x16x32_bf16(af[f], bfr[g], acc[f][g], 0, 0, 0);
    }

    #pragma unroll
    for (int f = 0; f < 4; ++f) {
        #pragma unroll
        for (int g = 0; g < 4; ++g) {
            int col = n0 + wn*64 + g*16 + cc;
            float bv = bias[col];
            int colw = (col & 511) * 4 + (col >> 9);
            #pragma unroll
            for (int i = 0; i < 4; ++i) {
                int row = m0 + wm*64 + f*16 + kg*4 + i;
                C[(size_t)row * G4 + colw] = f2bf(acc[f][g][i] + bv);
            }
        }
    }
}

// ================= persistent LSTM: 8 instances x 32 blocks =================
struct PCellN {
    ushort_t* rot;
    const ushort_t* B;
    const ushort_t* xp;     // L0 only: gate-interleaved, rows pre-offset
    const float* bias;
    float* hlast;
    const int* lens;
    int* flags;
    int* pflag;
    int K, T, layer;
};
struct PPackN { PCellN cell[8]; };

template<int N> __device__ __forceinline__ void vmwait() {
    if constexpr      (N == 0)  asm volatile("s_waitcnt vmcnt(0)"  ::: "memory");
    else if constexpr (N == 1)  asm volatile("s_waitcnt vmcnt(1)"  ::: "memory");
    else if constexpr (N == 2)  asm volatile("s_waitcnt vmcnt(2)"  ::: "memory");
    else if constexpr (N == 3)  asm volatile("s_waitcnt vmcnt(3)"  ::: "memory");
    else if constexpr (N == 4)  asm volatile("s_waitcnt vmcnt(4)"  ::: "memory");
    else if constexpr (N == 5)  asm volatile("s_waitcnt vmcnt(5)"  ::: "memory");
    else if constexpr (N == 6)  asm volatile("s_waitcnt vmcnt(6)"  ::: "memory");
    else if constexpr (N == 7)  asm volatile("s_waitcnt vmcnt(7)"  ::: "memory");
    else if constexpr (N == 8)  asm volatile("s_waitcnt vmcnt(8)"  ::: "memory");
    else if constexpr (N == 9)  asm volatile("s_waitcnt vmcnt(9)"  ::: "memory");
    else if constexpr (N == 10) asm volatile("s_waitcnt vmcnt(10)" ::: "memory");
    else if constexpr (N == 11) asm volatile("s_waitcnt vmcnt(11)" ::: "memory");
    else if constexpr (N == 12) asm volatile("s_waitcnt vmcnt(12)" ::: "memory");
    else if constexpr (N == 13) asm volatile("s_waitcnt vmcnt(13)" ::: "memory");
    else if constexpr (N == 14) asm volatile("s_waitcnt vmcnt(14)" ::: "memory");
    else                        asm volatile("s_waitcnt vmcnt(15)" ::: "memory");
}

template<int C, int NQ, int D>
__device__ __forceinline__ void aissN(uint4 (&ap)[D][NQ],
    const ushort_t* baseX, const ushort_t* baseH, const int* aoff)
{
    const ushort_t* b_ = (C * 32 < 512) ? baseX : baseH;
    #pragma unroll
    for (int q = 0; q < NQ; ++q)
        asm volatile("global_load_dwordx4 %0, %1, off"
            : "=v"(ap[C % D][q])
            : "v"((const char*)b_ + aoff[q] + C * 64));
}

template<int C, int D, int NQ>
__device__ __forceinline__ void prologueN(uint4 (&ap)[D][NQ],
    const ushort_t* bX, const ushort_t* bH, const int* aoff)
{
    if constexpr (C < D) {
        aissN<C, NQ, D>(ap, bX, bH, aoff);
        prologueN<C + 1, D, NQ>(ap, bX, bH, aoff);
    }
}

template<int C, int NC, int NQ, int D>
__device__ __forceinline__ void chunksN(uint4 (&ap)[D][NQ], f32x4 (&acc)[NQ][4],
    const ushort_t* bX, const ushort_t* bH, const int* aoff,
    const ushort_t* Bs, int cc, int kg, int swz)
{
    if constexpr (C < NC) {
        constexpr int infl = (NC - 1 - C) > (D - 1) ? (D - 1) : (NC - 1 - C);
        vmwait<infl * NQ>();
        __builtin_amdgcn_sched_barrier(0);
        bf16x8 bfr[4];
        #pragma unroll
        for (int g = 0; g < 4; ++g) {
            int boff = ((g*16 + cc) * (NC*64) + C*64 + kg*16) ^ swz;
            bfr[g] = *(const bf16x8*)((const char*)Bs + boff);
        }
        #pragma unroll
        for (int q = 0; q < NQ; ++q)
            #pragma unroll
            for (int g = 0; g < 4; ++g)
                acc[q][g] = __builtin_amdgcn_mfma_f32_16x16x32_bf16(
                    *(const bf16x8*)&ap[C % D][q], bfr[g], acc[q][g], 0, 0, 0);
        if constexpr (C + D < NC) aissN<C + D, NQ, D>(ap, bX, bH, aoff);
        chunksN<C + 1, NC, NQ, D>(ap, acc, bX, bH, aoff, Bs, cc, kg, swz);
    }
}

// prefetch all xp gate-addends for step t into LDS (24 x 4B global_load_lds,
// zero VGPR cost, off the GEMM's vmcnt critical path; lane-private slots).
__device__ __forceinline__ void prefetch_xp(
    const ushort_t* xp, unsigned* xps, int T, int tq0, int nq,
    int kg, int j, int wv, int t)
{
    for (int q = 0; q < nq; ++q) {
        #pragma unroll
        for (int i = 0; i < 4; ++i) {
            const int n = (tq0 + q)*16 + kg*4 + i;
            const char* src = (const char*)xp + ((size_t)n*T + t)*4096 + (size_t)j*8;
            #pragma unroll
            for (int w2 = 0; w2 < 2; ++w2) {
                unsigned* dst = xps + ((q*4 + i)*2 + w2)*256 + wv*64;
                __builtin_amdgcn_global_load_lds(
                    (const __attribute__((address_space(1))) unsigned int*)(src + w2*4),
                    (__attribute__((address_space(3))) unsigned int*)dst, 4, 0, 0);
            }
        }
    }
}

template<int NC, int NQ, int D>
__device__ __forceinline__ void step_work(
    const ushort_t* __restrict__ baseX,
    const ushort_t* __restrict__ baseH,
    const ushort_t* __restrict__ Bs,
    const unsigned* __restrict__ xpsT,    // xps + tid (null-able semantics via hasXp)
    int hasXp,
    const float* __restrict__ bias_r,
    ushort_t* __restrict__ Ost,
    float* __restrict__ hlast,
    const unsigned* __restrict__ lr,
    float (&creg)[3][4],
    int t, int tq0, int lane, int j)
{
    const int cc = lane & 15, kg = lane >> 4;
    const int swz = (cc & 7) << 4;

    int aoff[NQ];
    #pragma unroll
    for (int q = 0; q < NQ; ++q)
        aoff[q] = ((tq0 + q)*16 + cc)*2048 + kg*16;

    f32x4 acc[NQ][4];
    #pragma unroll
    for (int q = 0; q < NQ; ++q)
        #pragma unroll
        for (int g = 0; g < 4; ++g)
            acc[q][g] = (f32x4){0.f, 0.f, 0.f, 0.f};

    uint4 ap[D][NQ];
    prologueN<0, D, NQ>(ap, baseX, baseH, aoff);
    chunksN<0, NC, NQ, D>(ap, acc, baseX, baseH, aoff, Bs, cc, kg, swz);
    __builtin_amdgcn_sched_barrier(0);

    #pragma unroll
    for (int q = 0; q < NQ; ++q) {
        const unsigned lq = lr[q];
        #pragma unroll
        for (int i = 0; i < 4; ++i) {
            const int n = (tq0 + q)*16 + kg*4 + i;
            float g0 = acc[q][0][i], g1 = acc[q][1][i];
            float g2 = acc[q][2][i], g3 = acc[q][3][i];
            if (hasXp) {
                unsigned lo = xpsT[((q*4 + i)*2 + 0)*256];
                unsigned hi = xpsT[((q*4 + i)*2 + 1)*256];
                g0 += __uint_as_float(lo << 16);
                g1 += __uint_as_float(lo & 0xFFFF0000u);
                g2 += __uint_as_float(hi << 16);
                g3 += __uint_as_float(hi & 0xFFFF0000u);
            } else {
                g0 += bias_r[0]; g1 += bias_r[1];
                g2 += bias_r[2]; g3 += bias_r[3];
            }
            float cn = sigmoidf_(g1) * creg[q][i] + sigmoidf_(g0) * tanhf(g2);
            creg[q][i] = cn;
            float h = sigmoidf_(g3) * tanhf(cn);
            unsigned hb = (unsigned)f2bf(h);
            unsigned pb = (unsigned)__shfl_xor((int)hb, 1);
            if ((cc & 1) == 0) {
                ushort_t* oa = Ost + (size_t)n * 1024 + j;
                asm volatile("global_store_dword %0, %1, off sc0 sc1"
                             :: "v"(oa), "v"(hb | (pb << 16)));
            }
            if (hlast && t == (int)((lq >> (8*i)) & 0xFF) - 1)
                hlast[(size_t)n * HDIM + j] = h;
        }
    }
}

__global__ __launch_bounds__(256) void lstm_persist_kernel(PPackN P)
{
    const int inst = blockIdx.x & 7;
    const int blk  = blockIdx.x >> 3;     // 0..31 -> j-slice of 16
    const PCellN cl = P.cell[inst];

    const int tid  = threadIdx.x;
    const int w    = tid >> 6;
    const int lane = tid & 63;
    const int cc   = lane & 15;
    const int kg   = lane >> 4;
    const int j0   = blk * 16;
    const int j    = j0 + cc;
    const int K = cl.K, T = cl.T;
    const int nq  = (w < 2) ? 3 : 2;
    const int tq0 = (w < 2) ? w*3 : 6 + (w - 2)*2;

    __shared__ ushort_t Bs[64 * 1024];          // 128 KB
    __shared__ unsigned xps[24 * 256];          // 24 KB xp stage (L0 only)
    const unsigned* xpsT = xps + tid;

    {
        const int CH = K >> 3;
        const int tot = 64 * CH;
        for (int idx = tid; idx < tot; idx += 256) {
            int r = idx / CH, ch = idx - r * CH;
            int gr = (r >> 4) * HDIM + j0 + (r & 15);
            int dst = (idx * 16) ^ ((r & 7) << 4);
            *(u32x4*)((char*)Bs + dst) = *(const u32x4*)(cl.B + (size_t)gr * K + ch * 8);
        }
    }

    const int hasXp = (cl.xp != nullptr);
    if (hasXp) prefetch_xp(cl.xp, xps, T, tq0, nq, kg, j, w, 0);

    float bias_r[4] = {0.f, 0.f, 0.f, 0.f};
    if (cl.bias) {
        #pragma unroll
        for (int g = 0; g < 4; ++g) bias_r[g] = cl.bias[g * HDIM + j];
    }

    unsigned lr[3] = {0u, 0u, 0u};
    #pragma unroll
    for (int q = 0; q < 3; ++q) {
        if (q < nq) {
            unsigned pkd = 0;
            #pragma unroll
            for (int i = 0; i < 4; ++i)
                pkd |= ((unsigned)cl.lens[(tq0 + q)*16 + kg*4 + i] & 0xFF) << (8*i);
            lr[q] = pkd;
        }
    }

    float creg[3][4];
    #pragma unroll
    for (int q = 0; q < 3; ++q)
        #pragma unroll
        for (int i = 0; i < 4; ++i) creg[q][i] = 0.f;

    asm volatile("s_waitcnt vmcnt(0)" ::: "memory");  // B preload + xp(0) staged
    __syncthreads();

    for (int ss = 0; ss <= T; ++ss) {
        const bool active = cl.layer ? (ss >= 1) : (ss < T);
        if (active) {
            const int t = cl.layer ? (ss - 1) : ss;
            const ushort_t* baseX; const ushort_t* baseH; ushort_t* Ost;
            if (cl.layer == 0) {
                baseX = cl.rot + (size_t)t * BUFU;
                baseH = baseX;
                Ost   = cl.rot + (size_t)(t + 1) * BUFU;
            } else {
                baseX = cl.rot + (size_t)(t + 1) * BUFU;
                baseH = cl.rot + (size_t)t * BUFU;
                Ost   = cl.rot + (size_t)(t + 1) * BUFU + HDIM;
            }
            if (K == 512) {
                if (w < 2) step_work<16,3,6>(baseX, baseH, Bs, xpsT, hasXp, bias_r, Ost, cl.hlast, lr, creg, t, tq0, lane, j);
                else       step_work<16,2,8>(baseX, baseH, Bs, xpsT, hasXp, bias_r, Ost, cl.hlast, lr, creg, t, tq0, lane, j);
            } else {
                if (w < 2) step_work<32,3,6>(baseX, baseH, Bs, xpsT, hasXp, bias_r, Ost, cl.hlast, lr, creg, t, tq0, lane, j);
                else       step_work<32,2,8>(baseX, baseH, Bs, xpsT, hasXp, bias_r, Ost, cl.hlast, lr, creg, t, tq0, lane, j);
            }
            // prefetch next step's xp (lane-private LDS slots; epilogue above
            // already consumed this step's values). Completes under barrier.
            if (hasXp && t + 1 < T)
                prefetch_xp(cl.xp, xps, T, tq0, nq, kg, j, w, t + 1);
        }
        if (ss < T) {
            asm volatile("s_waitcnt vmcnt(0)" ::: "memory");  // h stores + xp stage
            __syncthreads();
            if (tid == 0) {
                int* fa = cl.flags + blk;
                int vv = ss + 1;
                asm volatile("global_store_dword %0, %1, off sc0 sc1"
                             :: "v"(fa), "v"(vv) : "memory");
            }
            if (w == 0) {
                // fused poll: lanes 0..31 -> flags, lane 32 -> pflag (L1 only)
                const int* pa = (lane < 32) ? (cl.flags + lane) : cl.pflag;
                const bool chk = (lane < 32) || (cl.layer == 1 && lane == 32);
                int spins = 0; bool ok;
                do {
                    int v;
                    asm volatile("global_load_dword %0, %1, off sc0 sc1"
                                 : "=v"(v) : "v"(pa) : "memory");
                    asm volatile("s_waitcnt vmcnt(0)" ::: "memory");
                    ok = (bool)__all(!chk || v >= ss + 1);
                    if (!ok) __builtin_amdgcn_s_sleep(1);
                } while (!ok && ++spins < (1 << 20));
                if (cl.layer == 0 && blk == 0 && lane == 0) {
                    int vv = ss + 1;
                    asm volatile("global_store_dword %0, %1, off sc0 sc1"
                                 :: "v"(cl.pflag), "v"(vv) : "memory");
                }
            }
            __syncthreads();
        }
    }
}

// ---------------- nz flags ----------------
__global__ __launch_bounds__(64) void nz_kernel(
    const float* __restrict__ he, int* __restrict__ nz)
{
    int rr = blockIdx.x;
    int lane = threadIdx.x;
    const float* row = he + (size_t)rr * HDIM;
    bool any = false;
    for (int k = lane; k < HDIM; k += 64) any |= (row[k] != 0.0f);
    unsigned long long b = __ballot(any);
    if (lane == 0) nz[rr] = (b != 0ull) ? 1 : 0;
}

// ---------------- text_rel expansion ----------------
__global__ __launch_bounds__(256) void expand_kernel(
    const float* __restrict__ he, const int* __restrict__ nz,
    float* __restrict__ out)
{
    int blk = blockIdx.x;               // ((b*10+i)*10+j)*10+k
    int k = blk % 10;
    int j = (blk / 10) % 10;
    int i = (blk / 100) % 10;
    int b = blk / 1000;
    int tid = threadIdx.x;
    float4* o = (float4*)(out + (size_t)blk * 1024);
    float4 z; z.x = z.y = z.z = z.w = 0.0f;
    if (tid < 128) {
        bool m = (j <= i) && (k <= i) && (nz[b*10 + k] != 0);
        float4 v = m ? ((const float4*)(he + (size_t)(b*10 + j) * HDIM))[tid] : z;
        o[tid] = v;
    } else {
        int c = tid - 128;
        bool m = (k <= i) && (j <= i) && (nz[b*10 + j] != 0);
        float4 v = m ? ((const float4*)(he + (size_t)(b*10 + k) * HDIM))[c] : z;
        o[128 + c] = v;
    }
}

extern "C" void kernel_launch(void* const* d_in, const int* in_sizes, int n_in,
                              void* d_out, int out_size, void* d_ws, size_t ws_size,
                              hipStream_t stream)
{
    (void)in_sizes; (void)n_in; (void)out_size; (void)ws_size;
    const int* ques     = (const int*)d_in[0];
    const int* hist     = (const int*)d_in[1];
    const int* ques_len = (const int*)d_in[2];
    const int* hist_len = (const int*)d_in[3];
    const float* w_emb  = (const float*)d_in[6];
    const float* elmo   = (const float*)d_in[7];
    const float* Wc     = (const float*)d_in[8];
    const float* bc     = (const float*)d_in[9];

    // ---- workspace layout ----
    char* ws = (char*)d_ws;
    size_t off = 0;
    auto alloc = [&](size_t bytes) { char* p = ws + off; off += (bytes + 255) & ~(size_t)255; return p; };
    ushort_t* XP0bf = (ushort_t*)alloc((size_t)19200 * G4 * 2);      // 78.6 MB

    const size_t rotSlice = (size_t)41 * BUFU * 2;                   // 13.4 MB
    char* uni = alloc(4 * rotSlice);                                 // 53.7 MB >= Xb 32.0 MB
    ushort_t* Xb = (ushort_t*)uni;
    auto rotPtr = [&](int s, int v) { return (ushort_t*)(uni + (size_t)(s*2 + v) * rotSlice); };

    ushort_t* Wcb = (ushort_t*)alloc((size_t)HDIM * ELMOD * 2);
    ushort_t *Wih0b[2], *Whh0b[2], *Wcat[2];
    for (int s = 0; s < 2; ++s) {
        Wih0b[s] = (ushort_t*)alloc((size_t)G4 * XPAD * 2);
        Whh0b[s] = (ushort_t*)alloc((size_t)G4 * HDIM * 2);
        Wcat[s]  = (ushort_t*)alloc((size_t)G4 * ELMOD * 2);
    }
    int* tokcat = (int*)alloc(19200 * 4);
    int* ctrs = (int*)alloc(4096);
    float* he = (float*)alloc((size_t)NSEQ * HDIM * 4);
    int* nzb  = (int*)alloc(NSEQ * 4);

    float* out = (float*)d_out;
    float* ques_embed = out;
    float* text_rel   = out + (size_t)NSEQ * HDIM;

    const int rowoff[2] = {0, 6400};
    const int TT[2] = {20, 40};
    const int* lensp[2] = {ques_len, hist_len};

    // ---- all weight conversions: one launch ----
    ConvPack CP;
    {
        int ji = 0; long base = 0;
        auto addJob = [&](const float* src, ushort_t* dst, int sc, int ds, int doff, int fc, int rows) {
            CP.src[ji] = src; CP.dst[ji] = dst; CP.srcCols[ji] = sc; CP.dstStride[ji] = ds;
            CP.dstOff[ji] = doff; CP.fillCols[ji] = fc; CP.base[ji] = base;
            base += (long)fc * rows; ++ji;
        };
        addJob(Wc, Wcb, ELMOD, ELMOD, 0, ELMOD, HDIM);
        for (int s = 0; s < 2; ++s) {
            addJob((const float*)d_in[10 + 6*s], Wih0b[s], 812,  XPAD,  0,    XPAD, G4);
            addJob((const float*)d_in[11 + 6*s], Whh0b[s], HDIM, HDIM,  0,    HDIM, G4);
            addJob((const float*)d_in[13 + 6*s], Wcat[s],  HDIM, ELMOD, 0,    HDIM, G4);
            addJob((const float*)d_in[14 + 6*s], Wcat[s],  HDIM, ELMOD, HDIM, HDIM, G4);
        }
        CP.base[9] = base;
        int nblk = (int)((base + 255) / 256);
        conv_all_kernel<<<nblk, 256, 0, stream>>>(CP);
    }

    // ---- embeddings + input projections (read Xb BEFORE rot aliasing) ----
    emb_gather_kernel<<<19200, 128, 0, stream>>>(ques, hist, w_emb, Xb, tokcat);
    // elmo projection: single merged launch (shared weights)
    gemm_ff_kernel<<<dim3(HDIM/64, 19200/64), 256, 0, stream>>>(
        nullptr, elmo, tokcat, ELMOD, Wcb, bc, Xb + EMBD, XPAD, ELMOD, 0);
    for (int s = 0; s < 2; ++s) {
        int Ntok = NSEQ * TT[s];
        ushort_t* XbS = Xb + (size_t)rowoff[s] * XPAD;
        const float* b0 = (const float*)d_in[12 + 6*s];
        gemm_xp_kernel<<<dim3(G4/128, Ntok/128), 256, 0, stream>>>(
            XbS, Wih0b[s], b0, XP0bf + (size_t)rowoff[s] * G4);
    }

    // ---- zero rot[0] (h(-1)=0) + flags; AFTER Xb consumed (aliased) ----
    hipMemsetAsync(ctrs, 0, 4096, stream);
    for (int s = 0; s < 2; ++s)
        for (int v = 0; v < 2; ++v)
            hipMemsetAsync(rotPtr(s, v), 0, (size_t)BUFU * 2, stream);

    // ---- persistent LSTM: 256 blocks = 8 instances x 32 j-slices ----
    PPackN P;
    for (int layer = 0; layer < 2; ++layer)
        for (int s = 0; s < 2; ++s)
            for (int v = 0; v < 2; ++v) {
                int inst = layer*4 + s*2 + v;
                PCellN& c = P.cell[inst];
                c.rot   = rotPtr(s, v);
                c.B     = layer ? Wcat[s] : Whh0b[s];
                c.xp    = layer ? nullptr
                                : XP0bf + (size_t)(rowoff[s] + v*160*TT[s]) * G4;
                c.bias  = layer ? (const float*)d_in[15 + 6*s] : nullptr;
                c.hlast = layer ? ((s ? he : ques_embed) + (size_t)v*160*HDIM) : nullptr;
                c.lens  = lensp[s] + v*160;
                c.flags = ctrs + inst * 32;
                c.pflag = ctrs + 512 + (s*2 + v) * 32;
                c.K = layer ? ELMOD : HDIM;
                c.T = TT[s];
                c.layer = layer;
            }
    lstm_persist_kernel<<<256, 256, 0, stream>>>(P);

    // ---- expansion ----
    nz_kernel<<<NSEQ, 64, 0, stream>>>(he, nzb);
    expand_kernel<<<32000, 256, 0, stream>>>(he, nzb, text_rel);
}

// Round 15
// 954.786 us; speedup vs baseline: 1.1579x; 1.1579x over previous
//
#include <hip/hip_runtime.h>
#include <math.h>

#define NSEQ 320
#define HDIM 512
#define G4   2048
#define EMBD 300
#define ELMOD 1024
#define XPAD 832          // 812 padded to multiple of 32
#define BUFU (160*1024)   // ushorts per rotated h step-buffer (160 rows x 1024)

typedef __attribute__((ext_vector_type(8))) short bf16x8;
typedef __attribute__((ext_vector_type(4))) float f32x4;
typedef __attribute__((ext_vector_type(4))) unsigned int u32x4;
typedef __attribute__((ext_vector_type(2))) unsigned int u32x2;
typedef unsigned short ushort_t;

__device__ __forceinline__ float sigmoidf_(float x) { return 1.0f / (1.0f + expf(-x)); }

__device__ __forceinline__ ushort_t f2bf(float f) {
    unsigned u = __float_as_uint(f);
    u = (u + 0x7FFFu + ((u >> 16) & 1u)) >> 16;   // RNE
    return (ushort_t)u;
}
__device__ __forceinline__ unsigned pack2(float a, float b) {
    return (unsigned)f2bf(a) | ((unsigned)f2bf(b) << 16);
}

// ---------------- all weight conversions in ONE flat launch ----------------
struct ConvPack {
    const float* src[9];
    ushort_t* dst[9];
    int srcCols[9], dstStride[9], dstOff[9], fillCols[9];
    long base[10];
};

__global__ __launch_bounds__(256) void conv_all_kernel(ConvPack P)
{
    long gid = (long)blockIdx.x * 256 + threadIdx.x;
    if (gid >= P.base[9]) return;
    int job = 0;
    #pragma unroll
    for (int j = 1; j < 9; ++j) if (gid >= P.base[j]) job = j;
    int e  = (int)(gid - P.base[job]);
    int fc = P.fillCols[job];
    int r  = e / fc;
    int ci = e - r * fc;
    int sc = P.srcCols[job];
    float v = (ci < sc) ? P.src[job][(size_t)r * sc + ci] : 0.0f;
    P.dst[job][(size_t)r * P.dstStride[job] + P.dstOff[job] + ci] = f2bf(v);
}

// ---------------- GloVe gather (ques+hist merged) + tokcat ----------------
__global__ __launch_bounds__(128) void emb_gather_kernel(
    const int* __restrict__ ques, const int* __restrict__ hist,
    const float* __restrict__ w_emb, ushort_t* __restrict__ Xb,
    int* __restrict__ tokcat)
{
    int n = blockIdx.x;
    int tokid = (n < 6400) ? ques[n] : hist[n - 6400];
    int t = threadIdx.x;
    ushort_t* dst = Xb + (size_t)n * XPAD;
    if (t < 75) {
        const float4* src = (const float4*)(w_emb + (size_t)tokid * EMBD);
        float4 v = src[t];
        dst[4*t+0] = f2bf(v.x); dst[4*t+1] = f2bf(v.y);
        dst[4*t+2] = f2bf(v.z); dst[4*t+3] = f2bf(v.w);
    } else if (t >= 108) {  // 20 pad cols
        dst[812 + (t - 108)] = 0;
        if (t == 108) tokcat[n] = tokid;
    }
}

// ---------------- feed-forward GEMM (64x64 tile): elmo projection ----------------
__global__ __launch_bounds__(256) void gemm_ff_kernel(
    const ushort_t* __restrict__ Ab, const float* __restrict__ Af,
    const int* __restrict__ tok, int strideA,
    const ushort_t* __restrict__ W, const float* __restrict__ bias,
    ushort_t* __restrict__ C, int strideC, int K, int remap)
{
    __shared__ ushort_t As[64 * 40];
    __shared__ ushort_t Bs[64 * 40];
    const int m0 = blockIdx.y * 64;
    const int n0 = blockIdx.x * 64;
    const int tid = threadIdx.x;
    const int r  = tid >> 2;
    const int kq = (tid & 3) << 3;

    const ushort_t* arow_b = nullptr;
    const float*    arow_f = nullptr;
    if (Af) arow_f = Af + (size_t)tok[m0 + r] * strideA + kq;
    else    arow_b = Ab + (size_t)(m0 + r) * strideA + kq;
    const ushort_t* brow = W + (size_t)(n0 + r) * K + kq;

    const int lane = tid & 63;
    const int w = tid >> 6;
    const int wm = w & 1, wn = w >> 1;
    const int kc = (lane >> 4) << 3;

    f32x4 acc[2][2];
    #pragma unroll
    for (int f = 0; f < 2; ++f)
        #pragma unroll
        for (int g = 0; g < 2; ++g)
            acc[f][g] = (f32x4){0.f, 0.f, 0.f, 0.f};

    for (int k0 = 0; k0 < K; k0 += 32) {
        if (Af) {
            float4 v0 = ((const float4*)(arow_f + k0))[0];
            float4 v1 = ((const float4*)(arow_f + k0))[1];
            uint4 p; p.x = pack2(v0.x, v0.y); p.y = pack2(v0.z, v0.w);
            p.z = pack2(v1.x, v1.y); p.w = pack2(v1.z, v1.w);
            *(uint4*)&As[r*40 + kq] = p;
        } else {
            *(uint4*)&As[r*40 + kq] = *(const uint4*)(arow_b + k0);
        }
        *(uint4*)&Bs[r*40 + kq] = *(const uint4*)(brow + k0);
        __syncthreads();
        bf16x8 af[2], bfr[2];
        #pragma unroll
        for (int f = 0; f < 2; ++f)
            af[f] = *(const bf16x8*)&As[(wm*32 + f*16 + (lane & 15))*40 + kc];
        #pragma unroll
        for (int g = 0; g < 2; ++g)
            bfr[g] = *(const bf16x8*)&Bs[(wn*32 + g*16 + (lane & 15))*40 + kc];
        #pragma unroll
        for (int f = 0; f < 2; ++f)
            #pragma unroll
            for (int g = 0; g < 2; ++g)
                acc[f][g] = __builtin_amdgcn_mfma_f32_16x16x32_bf16(af[f], bfr[g], acc[f][g], 0, 0, 0);
        __syncthreads();
    }

    #pragma unroll
    for (int f = 0; f < 2; ++f) {
        #pragma unroll
        for (int g = 0; g < 2; ++g) {
            int col = n0 + wn*32 + g*16 + (lane & 15);
            float bv = bias[col];
            int colw = remap ? ((col & 511) * 4 + (col >> 9)) : col;
            #pragma unroll
            for (int i = 0; i < 4; ++i) {
                int row = m0 + wm*32 + f*16 + ((lane >> 4) << 2) + i;
                C[(size_t)row * strideC + colw] = f2bf(acc[f][g][i] + bv);
            }
        }
    }
}

// ---------------- XP0 GEMM: 128x128 tile, global_load_lds staging ----------------
__global__ __launch_bounds__(256) void gemm_xp_kernel(
    const ushort_t* __restrict__ A,       // bf16 [M][XPAD]
    const ushort_t* __restrict__ W,       // bf16 [2048][XPAD]
    const float* __restrict__ bias,       // [2048]
    ushort_t* __restrict__ C)             // [M][2048] gate-interleaved cols
{
    __shared__ ushort_t As[128 * 32];
    __shared__ ushort_t Bs[128 * 32];
    const int m0 = blockIdx.y * 128;
    const int n0 = blockIdx.x * 128;
    const int tid = threadIdx.x;
    const int w = tid >> 6, lane = tid & 63;
    const int wm = w & 1, wn = w >> 1;
    const int cc = lane & 15, kg = lane >> 4;
    const int srow = lane >> 2;
    const int skc  = lane & 3;

    f32x4 acc[4][4];
    #pragma unroll
    for (int f = 0; f < 4; ++f)
        #pragma unroll
        for (int g = 0; g < 4; ++g)
            acc[f][g] = (f32x4){0.f, 0.f, 0.f, 0.f};

    for (int k0 = 0; k0 < XPAD; k0 += 32) {
        __syncthreads();
        #pragma unroll
        for (int i = 0; i < 2; ++i) {
            const int r = w*16 + i*64;
            const ushort_t* ga = A + (size_t)(m0 + r + srow) * XPAD + k0 + skc*8;
            ushort_t* la = &As[r * 32];
            __builtin_amdgcn_global_load_lds(
                (const __attribute__((address_space(1))) unsigned int*)ga,
                (__attribute__((address_space(3))) unsigned int*)la, 16, 0, 0);
            const ushort_t* gb = W + (size_t)(n0 + r + srow) * XPAD + k0 + skc*8;
            ushort_t* lb = &Bs[r * 32];
            __builtin_amdgcn_global_load_lds(
                (const __attribute__((address_space(1))) unsigned int*)gb,
                (__attribute__((address_space(3))) unsigned int*)lb, 16, 0, 0);
        }
        asm volatile("s_waitcnt vmcnt(0)");
        __syncthreads();
        bf16x8 af[4], bfr[4];
        #pragma unroll
        for (int f = 0; f < 4; ++f)
            af[f] = *(const bf16x8*)&As[(wm*64 + f*16 + cc)*32 + kg*8];
        #pragma unroll
        for (int g = 0; g < 4; ++g)
            bfr[g] = *(const bf16x8*)&Bs[(wn*64 + g*16 + cc)*32 + kg*8];
        #pragma unroll
        for (int f = 0; f < 4; ++f)
            #pragma unroll
            for (int g = 0; g < 4; ++g)
                acc[f][g] = __builtin_amdgcn_mfma_f32_16x16x32_bf16(af[f], bfr[g], acc[f][g], 0, 0, 0);
    }

    #pragma unroll
    for (int f = 0; f < 4; ++f) {
        #pragma unroll
        for (int g = 0; g < 4; ++g) {
            int col = n0 + wn*64 + g*16 + cc;
            float bv = bias[col];
            int colw = (col & 511) * 4 + (col >> 9);
            #pragma unroll
            for (int i = 0; i < 4; ++i) {
                int row = m0 + wm*64 + f*16 + kg*4 + i;
                C[(size_t)row * G4 + colw] = f2bf(acc[f][g][i] + bv);
            }
        }
    }
}

// ================= persistent LSTM: 8 instances x 32 blocks (r13-exact) =================
struct PCellN {
    ushort_t* rot;
    const ushort_t* B;
    const ushort_t* xp;     // L0 only: gate-interleaved, rows pre-offset
    const float* bias;
    float* hlast;
    const int* lens;
    int* flags;
    int* pflag;
    int K, T, layer;
};
struct PPackN { PCellN cell[8]; };

template<int N> __device__ __forceinline__ void vmwait() {
    if constexpr      (N == 0)  asm volatile("s_waitcnt vmcnt(0)"  ::: "memory");
    else if constexpr (N == 1)  asm volatile("s_waitcnt vmcnt(1)"  ::: "memory");
    else if constexpr (N == 2)  asm volatile("s_waitcnt vmcnt(2)"  ::: "memory");
    else if constexpr (N == 3)  asm volatile("s_waitcnt vmcnt(3)"  ::: "memory");
    else if constexpr (N == 4)  asm volatile("s_waitcnt vmcnt(4)"  ::: "memory");
    else if constexpr (N == 5)  asm volatile("s_waitcnt vmcnt(5)"  ::: "memory");
    else if constexpr (N == 6)  asm volatile("s_waitcnt vmcnt(6)"  ::: "memory");
    else if constexpr (N == 7)  asm volatile("s_waitcnt vmcnt(7)"  ::: "memory");
    else if constexpr (N == 8)  asm volatile("s_waitcnt vmcnt(8)"  ::: "memory");
    else if constexpr (N == 9)  asm volatile("s_waitcnt vmcnt(9)"  ::: "memory");
    else if constexpr (N == 10) asm volatile("s_waitcnt vmcnt(10)" ::: "memory");
    else if constexpr (N == 11) asm volatile("s_waitcnt vmcnt(11)" ::: "memory");
    else if constexpr (N == 12) asm volatile("s_waitcnt vmcnt(12)" ::: "memory");
    else if constexpr (N == 13) asm volatile("s_waitcnt vmcnt(13)" ::: "memory");
    else if constexpr (N == 14) asm volatile("s_waitcnt vmcnt(14)" ::: "memory");
    else                        asm volatile("s_waitcnt vmcnt(15)" ::: "memory");
}

template<int C, int NQ, int D>
__device__ __forceinline__ void aissN(uint4 (&ap)[D][NQ],
    const ushort_t* baseX, const ushort_t* baseH, const int* aoff)
{
    const ushort_t* b_ = (C * 32 < 512) ? baseX : baseH;
    #pragma unroll
    for (int q = 0; q < NQ; ++q)
        asm volatile("global_load_dwordx4 %0, %1, off"
            : "=v"(ap[C % D][q])
            : "v"((const char*)b_ + aoff[q] + C * 64));
}

template<int C, int D, int NQ>
__device__ __forceinline__ void prologueN(uint4 (&ap)[D][NQ],
    const ushort_t* bX, const ushort_t* bH, const int* aoff)
{
    if constexpr (C < D) {
        aissN<C, NQ, D>(ap, bX, bH, aoff);
        prologueN<C + 1, D, NQ>(ap, bX, bH, aoff);
    }
}

template<int C, int NC, int NQ, int D>
__device__ __forceinline__ void chunksN(uint4 (&ap)[D][NQ], f32x4 (&acc)[NQ][4],
    const ushort_t* bX, const ushort_t* bH, const int* aoff,
    const ushort_t* Bs, int cc, int kg, int swz)
{
    if constexpr (C < NC) {
        constexpr int infl = (NC - 1 - C) > (D - 1) ? (D - 1) : (NC - 1 - C);
        vmwait<infl * NQ>();
        __builtin_amdgcn_sched_barrier(0);
        bf16x8 bfr[4];
        #pragma unroll
        for (int g = 0; g < 4; ++g) {
            int boff = ((g*16 + cc) * (NC*64) + C*64 + kg*16) ^ swz;
            bfr[g] = *(const bf16x8*)((const char*)Bs + boff);
        }
        #pragma unroll
        for (int q = 0; q < NQ; ++q)
            #pragma unroll
            for (int g = 0; g < 4; ++g)
                acc[q][g] = __builtin_amdgcn_mfma_f32_16x16x32_bf16(
                    *(const bf16x8*)&ap[C % D][q], bfr[g], acc[q][g], 0, 0, 0);
        if constexpr (C + D < NC) aissN<C + D, NQ, D>(ap, bX, bH, aoff);
        chunksN<C + 1, NC, NQ, D>(ap, acc, bX, bH, aoff, Bs, cc, kg, swz);
    }
}

template<int NC, int NQ, int D>
__device__ __forceinline__ void step_work(
    const ushort_t* __restrict__ baseX,
    const ushort_t* __restrict__ baseH,
    const ushort_t* __restrict__ Bs,
    const ushort_t* __restrict__ xp,
    const float* __restrict__ bias_r,
    ushort_t* __restrict__ Ost,
    float* __restrict__ hlast,
    const unsigned* __restrict__ lr,
    float (&creg)[3][4],
    int t, int T, int tq0, int lane, int j)
{
    const int cc = lane & 15, kg = lane >> 4;
    const int swz = (cc & 7) << 4;

    int aoff[NQ];
    #pragma unroll
    for (int q = 0; q < NQ; ++q)
        aoff[q] = ((tq0 + q)*16 + cc)*2048 + kg*16;

    u32x2 xpk[NQ][4];
    if (xp) {
        #pragma unroll
        for (int q = 0; q < NQ; ++q)
            #pragma unroll
            for (int i = 0; i < 4; ++i) {
                const int n = (tq0 + q)*16 + kg*4 + i;
                asm volatile("global_load_dwordx2 %0, %1, off"
                    : "=v"(xpk[q][i])
                    : "v"((const char*)xp + ((size_t)n*T + t)*4096 + (size_t)j*8));
            }
    }

    f32x4 acc[NQ][4];
    #pragma unroll
    for (int q = 0; q < NQ; ++q)
        #pragma unroll
        for (int g = 0; g < 4; ++g)
            acc[q][g] = (f32x4){0.f, 0.f, 0.f, 0.f};

    uint4 ap[D][NQ];
    prologueN<0, D, NQ>(ap, baseX, baseH, aoff);
    chunksN<0, NC, NQ, D>(ap, acc, baseX, baseH, aoff, Bs, cc, kg, swz);
    __builtin_amdgcn_sched_barrier(0);

    #pragma unroll
    for (int q = 0; q < NQ; ++q) {
        const unsigned lq = lr[q];
        #pragma unroll
        for (int i = 0; i < 4; ++i) {
            const int n = (tq0 + q)*16 + kg*4 + i;
            float g0 = acc[q][0][i], g1 = acc[q][1][i];
            float g2 = acc[q][2][i], g3 = acc[q][3][i];
            if (xp) {
                u32x2 xv = xpk[q][i];
                g0 += __uint_as_float(xv.x << 16);
                g1 += __uint_as_float(xv.x & 0xFFFF0000u);
                g2 += __uint_as_float(xv.y << 16);
                g3 += __uint_as_float(xv.y & 0xFFFF0000u);
            } else {
                g0 += bias_r[0]; g1 += bias_r[1];
                g2 += bias_r[2]; g3 += bias_r[3];
            }
            float cn = sigmoidf_(g1) * creg[q][i] + sigmoidf_(g0) * tanhf(g2);
            creg[q][i] = cn;
            float h = sigmoidf_(g3) * tanhf(cn);
            unsigned hb = (unsigned)f2bf(h);
            unsigned pb = (unsigned)__shfl_xor((int)hb, 1);
            if ((cc & 1) == 0) {
                ushort_t* oa = Ost + (size_t)n * 1024 + j;
                asm volatile("global_store_dword %0, %1, off sc0 sc1"
                             :: "v"(oa), "v"(hb | (pb << 16)));
            }
            if (hlast && t == (int)((lq >> (8*i)) & 0xFF) - 1)
                hlast[(size_t)n * HDIM + j] = h;
        }
    }
}

__global__ __launch_bounds__(256) void lstm_persist_kernel(PPackN P)
{
    const int inst = blockIdx.x & 7;
    const int blk  = blockIdx.x >> 3;     // 0..31 -> j-slice of 16
    const PCellN cl = P.cell[inst];

    const int tid  = threadIdx.x;
    const int w    = tid >> 6;
    const int lane = tid & 63;
    const int cc   = lane & 15;
    const int kg   = lane >> 4;
    const int j0   = blk * 16;
    const int j    = j0 + cc;
    const int K = cl.K, T = cl.T;
    const int nq  = (w < 2) ? 3 : 2;
    const int tq0 = (w < 2) ? w*3 : 6 + (w - 2)*2;

    __shared__ ushort_t Bs[64 * 1024];

    {
        const int CH = K >> 3;
        const int tot = 64 * CH;
        for (int idx = tid; idx < tot; idx += 256) {
            int r = idx / CH, ch = idx - r * CH;
            int gr = (r >> 4) * HDIM + j0 + (r & 15);
            int dst = (idx * 16) ^ ((r & 7) << 4);
            *(u32x4*)((char*)Bs + dst) = *(const u32x4*)(cl.B + (size_t)gr * K + ch * 8);
        }
    }

    float bias_r[4] = {0.f, 0.f, 0.f, 0.f};
    if (cl.bias) {
        #pragma unroll
        for (int g = 0; g < 4; ++g) bias_r[g] = cl.bias[g * HDIM + j];
    }

    unsigned lr[3] = {0u, 0u, 0u};
    #pragma unroll
    for (int q = 0; q < 3; ++q) {
        if (q < nq) {
            unsigned pkd = 0;
            #pragma unroll
            for (int i = 0; i < 4; ++i)
                pkd |= ((unsigned)cl.lens[(tq0 + q)*16 + kg*4 + i] & 0xFF) << (8*i);
            lr[q] = pkd;
        }
    }

    float creg[3][4];
    #pragma unroll
    for (int q = 0; q < 3; ++q)
        #pragma unroll
        for (int i = 0; i < 4; ++i) creg[q][i] = 0.f;

    __syncthreads();

    for (int ss = 0; ss <= T; ++ss) {
        const bool active = cl.layer ? (ss >= 1) : (ss < T);
        if (active) {
            const int t = cl.layer ? (ss - 1) : ss;
            const ushort_t* baseX; const ushort_t* baseH; ushort_t* Ost;
            if (cl.layer == 0) {
                baseX = cl.rot + (size_t)t * BUFU;
                baseH = baseX;
                Ost   = cl.rot + (size_t)(t + 1) * BUFU;
            } else {
                baseX = cl.rot + (size_t)(t + 1) * BUFU;
                baseH = cl.rot + (size_t)t * BUFU;
                Ost   = cl.rot + (size_t)(t + 1) * BUFU + HDIM;
            }
            if (K == 512) {
                if (w < 2) step_work<16,3,6>(baseX, baseH, Bs, cl.xp, bias_r, Ost, cl.hlast, lr, creg, t, T, tq0, lane, j);
                else       step_work<16,2,8>(baseX, baseH, Bs, cl.xp, bias_r, Ost, cl.hlast, lr, creg, t, T, tq0, lane, j);
            } else {
                if (w < 2) step_work<32,3,6>(baseX, baseH, Bs, cl.xp, bias_r, Ost, cl.hlast, lr, creg, t, T, tq0, lane, j);
                else       step_work<32,2,8>(baseX, baseH, Bs, cl.xp, bias_r, Ost, cl.hlast, lr, creg, t, T, tq0, lane, j);
            }
        }
        if (ss < T) {
            asm volatile("s_waitcnt vmcnt(0)" ::: "memory");
            __syncthreads();
            if (tid == 0) {
                int* fa = cl.flags + blk;
                int vv = ss + 1;
                asm volatile("global_store_dword %0, %1, off sc0 sc1"
                             :: "v"(fa), "v"(vv) : "memory");
            }
            if (w == 0) {
                const int* fa = cl.flags + (lane & 31);
                int spins = 0; bool ok;
                do {
                    int v;
                    asm volatile("global_load_dword %0, %1, off sc0 sc1"
                                 : "=v"(v) : "v"(fa) : "memory");
                    asm volatile("s_waitcnt vmcnt(0)" ::: "memory");
                    ok = (bool)__all(v >= ss + 1);
                    if (!ok) __builtin_amdgcn_s_sleep(1);
                } while (!ok && ++spins < (1 << 20));
                if (cl.layer == 0) {
                    if (blk == 0 && lane == 0) {
                        int vv = ss + 1;
                        asm volatile("global_store_dword %0, %1, off sc0 sc1"
                                     :: "v"(cl.pflag), "v"(vv) : "memory");
                    }
                } else if (lane == 0) {
                    int spins2 = 0; int pv;
                    do {
                        asm volatile("global_load_dword %0, %1, off sc0 sc1"
                                     : "=v"(pv) : "v"((const int*)cl.pflag) : "memory");
                        asm volatile("s_waitcnt vmcnt(0)" ::: "memory");
                        if (pv < ss + 1) __builtin_amdgcn_s_sleep(1);
                    } while (pv < ss + 1 && ++spins2 < (1 << 20));
                }
            }
            __syncthreads();
        }
    }
}

// ---------------- nz flags ----------------
__global__ __launch_bounds__(64) void nz_kernel(
    const float* __restrict__ he, int* __restrict__ nz)
{
    int rr = blockIdx.x;
    int lane = threadIdx.x;
    const float* row = he + (size_t)rr * HDIM;
    bool any = false;
    for (int k = lane; k < HDIM; k += 64) any |= (row[k] != 0.0f);
    unsigned long long b = __ballot(any);
    if (lane == 0) nz[rr] = (b != 0ull) ? 1 : 0;
}

// ---------------- text_rel expansion ----------------
__global__ __launch_bounds__(256) void expand_kernel(
    const float* __restrict__ he, const int* __restrict__ nz,
    float* __restrict__ out)
{
    int blk = blockIdx.x;               // ((b*10+i)*10+j)*10+k
    int k = blk % 10;
    int j = (blk / 10) % 10;
    int i = (blk / 100) % 10;
    int b = blk / 1000;
    int tid = threadIdx.x;
    float4* o = (float4*)(out + (size_t)blk * 1024);
    float4 z; z.x = z.y = z.z = z.w = 0.0f;
    if (tid < 128) {
        bool m = (j <= i) && (k <= i) && (nz[b*10 + k] != 0);
        float4 v = m ? ((const float4*)(he + (size_t)(b*10 + j) * HDIM))[tid] : z;
        o[tid] = v;
    } else {
        int c = tid - 128;
        bool m = (k <= i) && (j <= i) && (nz[b*10 + j] != 0);
        float4 v = m ? ((const float4*)(he + (size_t)(b*10 + k) * HDIM))[c] : z;
        o[128 + c] = v;
    }
}

extern "C" void kernel_launch(void* const* d_in, const int* in_sizes, int n_in,
                              void* d_out, int out_size, void* d_ws, size_t ws_size,
                              hipStream_t stream)
{
    (void)in_sizes; (void)n_in; (void)out_size; (void)ws_size;
    const int* ques     = (const int*)d_in[0];
    const int* hist     = (const int*)d_in[1];
    const int* ques_len = (const int*)d_in[2];
    const int* hist_len = (const int*)d_in[3];
    const float* w_emb  = (const float*)d_in[6];
    const float* elmo   = (const float*)d_in[7];
    const float* Wc     = (const float*)d_in[8];
    const float* bc     = (const float*)d_in[9];

    // ---- workspace layout ----
    char* ws = (char*)d_ws;
    size_t off = 0;
    auto alloc = [&](size_t bytes) { char* p = ws + off; off += (bytes + 255) & ~(size_t)255; return p; };
    ushort_t* XP0bf = (ushort_t*)alloc((size_t)19200 * G4 * 2);      // 78.6 MB

    const size_t rotSlice = (size_t)41 * BUFU * 2;                   // 13.4 MB
    char* uni = alloc(4 * rotSlice);                                 // 53.7 MB >= Xb 32.0 MB
    ushort_t* Xb = (ushort_t*)uni;
    auto rotPtr = [&](int s, int v) { return (ushort_t*)(uni + (size_t)(s*2 + v) * rotSlice); };

    ushort_t* Wcb = (ushort_t*)alloc((size_t)HDIM * ELMOD * 2);
    ushort_t *Wih0b[2], *Whh0b[2], *Wcat[2];
    for (int s = 0; s < 2; ++s) {
        Wih0b[s] = (ushort_t*)alloc((size_t)G4 * XPAD * 2);
        Whh0b[s] = (ushort_t*)alloc((size_t)G4 * HDIM * 2);
        Wcat[s]  = (ushort_t*)alloc((size_t)G4 * ELMOD * 2);
    }
    int* tokcat = (int*)alloc(19200 * 4);
    int* ctrs = (int*)alloc(4096);
    float* he = (float*)alloc((size_t)NSEQ * HDIM * 4);
    int* nzb  = (int*)alloc(NSEQ * 4);

    float* out = (float*)d_out;
    float* ques_embed = out;
    float* text_rel   = out + (size_t)NSEQ * HDIM;

    const int rowoff[2] = {0, 6400};
    const int TT[2] = {20, 40};
    const int* lensp[2] = {ques_len, hist_len};

    // ---- all weight conversions: one launch ----
    ConvPack CP;
    {
        int ji = 0; long base = 0;
        auto addJob = [&](const float* src, ushort_t* dst, int sc, int ds, int doff, int fc, int rows) {
            CP.src[ji] = src; CP.dst[ji] = dst; CP.srcCols[ji] = sc; CP.dstStride[ji] = ds;
            CP.dstOff[ji] = doff; CP.fillCols[ji] = fc; CP.base[ji] = base;
            base += (long)fc * rows; ++ji;
        };
        addJob(Wc, Wcb, ELMOD, ELMOD, 0, ELMOD, HDIM);
        for (int s = 0; s < 2; ++s) {
            addJob((const float*)d_in[10 + 6*s], Wih0b[s], 812,  XPAD,  0,    XPAD, G4);
            addJob((const float*)d_in[11 + 6*s], Whh0b[s], HDIM, HDIM,  0,    HDIM, G4);
            addJob((const float*)d_in[13 + 6*s], Wcat[s],  HDIM, ELMOD, 0,    HDIM, G4);
            addJob((const float*)d_in[14 + 6*s], Wcat[s],  HDIM, ELMOD, HDIM, HDIM, G4);
        }
        CP.base[9] = base;
        int nblk = (int)((base + 255) / 256);
        conv_all_kernel<<<nblk, 256, 0, stream>>>(CP);
    }

    // ---- embeddings + input projections (read Xb BEFORE rot aliasing) ----
    emb_gather_kernel<<<19200, 128, 0, stream>>>(ques, hist, w_emb, Xb, tokcat);
    // elmo projection: single merged launch (shared weights)
    gemm_ff_kernel<<<dim3(HDIM/64, 19200/64), 256, 0, stream>>>(
        nullptr, elmo, tokcat, ELMOD, Wcb, bc, Xb + EMBD, XPAD, ELMOD, 0);
    for (int s = 0; s < 2; ++s) {
        int Ntok = NSEQ * TT[s];
        ushort_t* XbS = Xb + (size_t)rowoff[s] * XPAD;
        const float* b0 = (const float*)d_in[12 + 6*s];
        gemm_xp_kernel<<<dim3(G4/128, Ntok/128), 256, 0, stream>>>(
            XbS, Wih0b[s], b0, XP0bf + (size_t)rowoff[s] * G4);
    }

    // ---- zero rot[0] (h(-1)=0) + flags; AFTER Xb consumed (aliased) ----
    hipMemsetAsync(ctrs, 0, 4096, stream);
    for (int s = 0; s < 2; ++s)
        for (int v = 0; v < 2; ++v)
            hipMemsetAsync(rotPtr(s, v), 0, (size_t)BUFU * 2, stream);

    // ---- persistent LSTM: 256 blocks = 8 instances x 32 j-slices ----
    PPackN P;
    for (int layer = 0; layer < 2; ++layer)
        for (int s = 0; s < 2; ++s)
            for (int v = 0; v < 2; ++v) {
                int inst = layer*4 + s*2 + v;
                PCellN& c = P.cell[inst];
                c.rot   = rotPtr(s, v);
                c.B     = layer ? Wcat[s] : Whh0b[s];
                c.xp    = layer ? nullptr
                                : XP0bf + (size_t)(rowoff[s] + v*160*TT[s]) * G4;
                c.bias  = layer ? (const float*)d_in[15 + 6*s] : nullptr;
                c.hlast = layer ? ((s ? he : ques_embed) + (size_t)v*160*HDIM) : nullptr;
                c.lens  = lensp[s] + v*160;
                c.flags = ctrs + inst * 32;
                c.pflag = ctrs + 512 + (s*2 + v) * 32;
                c.K = layer ? ELMOD : HDIM;
                c.T = TT[s];
                c.layer = layer;
            }
    lstm_persist_kernel<<<256, 256, 0, stream>>>(P);

    // ---- expansion ----
    nz_kernel<<<NSEQ, 64, 0, stream>>>(he, nzb);
    expand_kernel<<<32000, 256, 0, stream>>>(he, nzb, text_rel);
}